// Round 1
// baseline (384.171 us; speedup 1.0000x reference)
//
#include <hip/hip_runtime.h>

#define DIM_ 1024
#define HEADS_ 16
#define HD_ 64
#define T_ 2048
#define BATCH_ 2
#define QKVN_ 3072

typedef unsigned short u16;
typedef float f32x4 __attribute__((ext_vector_type(4)));
typedef short s16x8 __attribute__((ext_vector_type(8)));
typedef unsigned short u16x4 __attribute__((ext_vector_type(4)));

__device__ __forceinline__ u16 f2bf(float f) {
  unsigned u = __float_as_uint(f);
  u += 0x7fffu + ((u >> 16) & 1u);
  return (u16)(u >> 16);
}

// ---------------- fp32 -> bf16 conversion ----------------
__global__ __launch_bounds__(256) void cvt_f32_bf16(const float* __restrict__ in,
                                                    u16* __restrict__ out, int n4) {
  int i = blockIdx.x * 256 + threadIdx.x;
  if (i >= n4) return;
  float4 v = reinterpret_cast<const float4*>(in)[i];
  u16x4 o;
  o.x = f2bf(v.x); o.y = f2bf(v.y); o.z = f2bf(v.z); o.w = f2bf(v.w);
  reinterpret_cast<u16x4*>(out)[i] = o;
}

// ---------------- async global->LDS helper ----------------
__device__ __forceinline__ void gld_lds16(const void* g, void* l) {
  auto gp = (__attribute__((address_space(1))) char*)(unsigned long long)g;
  auto lp = (__attribute__((address_space(3))) char*)(unsigned int)(unsigned long long)l;
  __builtin_amdgcn_global_load_lds(gp, lp, 16, 0, 0);
}

// ---------------- GEMM: C[M][N] = A[M][K] * B[N][K]^T (bf16 in, fp32 acc) ----------------
template <int OUTF32>
__global__ __launch_bounds__(256) void gemm_bt(const u16* __restrict__ A,
                                               const u16* __restrict__ B,
                                               void* __restrict__ Cv,
                                               int M, int N, int K) {
  __shared__ __align__(16) u16 As[128 * 32];
  __shared__ __align__(16) u16 Bs[128 * 32];
  const int tid = threadIdx.x;
  const int lane = tid & 63;
  const int w = tid >> 6;
  const int wr = w >> 1, wc = w & 1;
  const int lrow = lane & 15, kg = lane >> 4;
  const int nt = blockIdx.x, mt = blockIdx.y;
  const u16* Ag = A + (size_t)(mt * 128) * K;
  const u16* Bg = B + (size_t)(nt * 128) * K;

  f32x4 acc[4][4];
#pragma unroll
  for (int i = 0; i < 4; ++i)
#pragma unroll
    for (int j = 0; j < 4; ++j) {
      f32x4 z = {0.f, 0.f, 0.f, 0.f};
      acc[i][j] = z;
    }

  const int e0 = tid * 8;
  const int row0 = e0 >> 5, kc0 = e0 & 31;   // 128x32 tile, 8 elems/thread, 2 rounds
  const int row1 = row0 + 64, kc1 = kc0;
  const int ldsoff0 = (tid & ~63) * 16;
  const int ldsoff1 = (256 + (tid & ~63)) * 16;

  for (int k0 = 0; k0 < K; k0 += 32) {
    gld_lds16(Ag + (size_t)row0 * K + k0 + kc0, (char*)As + ldsoff0);
    gld_lds16(Ag + (size_t)row1 * K + k0 + kc1, (char*)As + ldsoff1);
    gld_lds16(Bg + (size_t)row0 * K + k0 + kc0, (char*)Bs + ldsoff0);
    gld_lds16(Bg + (size_t)row1 * K + k0 + kc1, (char*)Bs + ldsoff1);
    __syncthreads();
    s16x8 a[4], b[4];
#pragma unroll
    for (int mf = 0; mf < 4; ++mf)
      a[mf] = *(const s16x8*)&As[(wr * 64 + mf * 16 + lrow) * 32 + 8 * kg];
#pragma unroll
    for (int nf = 0; nf < 4; ++nf)
      b[nf] = *(const s16x8*)&Bs[(wc * 64 + nf * 16 + lrow) * 32 + 8 * kg];
#pragma unroll
    for (int mf = 0; mf < 4; ++mf)
#pragma unroll
      for (int nf = 0; nf < 4; ++nf)
        acc[mf][nf] = __builtin_amdgcn_mfma_f32_16x16x32_bf16(a[mf], b[nf], acc[mf][nf], 0, 0, 0);
    __syncthreads();
  }

#pragma unroll
  for (int mf = 0; mf < 4; ++mf)
#pragma unroll
    for (int nf = 0; nf < 4; ++nf)
#pragma unroll
      for (int j = 0; j < 4; ++j) {
        int r = mt * 128 + wr * 64 + mf * 16 + 4 * kg + j;
        int c = nt * 128 + wc * 64 + nf * 16 + lrow;
        float v = acc[mf][nf][j];
        if (OUTF32) ((float*)Cv)[(size_t)r * N + c] = v;
        else        ((u16*)Cv)[(size_t)r * N + c] = f2bf(v);
      }
}

// ---------------- V transpose: vt[b][h][d][t] = qkv[b*T+t][2048 + h*64 + d] ----------------
__global__ __launch_bounds__(256) void transpose_v(const u16* __restrict__ qkv,
                                                   u16* __restrict__ vt) {
  const int tt = blockIdx.x, bh = blockIdx.y;
  const int b = bh >> 4, h = bh & 15;
  const int d = threadIdx.x & 63;
  const int t16 = threadIdx.x >> 6;
  const int tbase = tt * 64 + t16 * 16;
  u16 tmp[16];
#pragma unroll
  for (int i = 0; i < 16; ++i)
    tmp[i] = qkv[(size_t)(b * T_ + tbase + i) * QKVN_ + 2048 + h * 64 + d];
  u16* dst = vt + (size_t)(bh * 64 + d) * T_ + tbase;
  *(s16x8*)dst = *(const s16x8*)tmp;
  *(s16x8*)(dst + 8) = *(const s16x8*)(tmp + 8);
}

// ---------------- causal flash attention ----------------
// grid (32 qtiles, 32 bh), 256 threads = 4 waves; wave w owns q rows [qt*64+w*16, +16)
__global__ __launch_bounds__(256) void attn_fwd(const u16* __restrict__ qkv,
                                                const u16* __restrict__ vt,
                                                u16* __restrict__ o) {
  const int qt = blockIdx.x, bh = blockIdx.y;
  const int b = bh >> 4, h = bh & 15;
  const int tid = threadIdx.x;
  const int w = tid >> 6, lane = tid & 63;
  const int lrow = lane & 15, kg = lane >> 4;
  const int qbase = qt * 64;
  __shared__ __align__(16) u16 plds[4][16][72];

  const size_t qoff = (size_t)(b * T_ + qbase + w * 16 + lrow) * QKVN_ + h * 64 + 8 * kg;
  const s16x8 aq0 = *(const s16x8*)&qkv[qoff];
  const s16x8 aq1 = *(const s16x8*)&qkv[qoff + 32];

  f32x4 oacc[4];
#pragma unroll
  for (int nf = 0; nf < 4; ++nf) {
    f32x4 z = {0.f, 0.f, 0.f, 0.f};
    oacc[nf] = z;
  }
  float mrun[4], lrun[4];
#pragma unroll
  for (int j = 0; j < 4; ++j) { mrun[j] = -__builtin_inff(); lrun[j] = 0.0f; }

  for (int kt = 0; kt <= qt; ++kt) {
    const int kvb = kt * 64;
    f32x4 sacc[4];
#pragma unroll
    for (int nf = 0; nf < 4; ++nf) {
      f32x4 z = {0.f, 0.f, 0.f, 0.f};
      sacc[nf] = z;
    }
#pragma unroll
    for (int nf = 0; nf < 4; ++nf) {
      const u16* kp = &qkv[(size_t)(b * T_ + kvb + nf * 16 + lrow) * QKVN_ + 1024 + h * 64 + 8 * kg];
      sacc[nf] = __builtin_amdgcn_mfma_f32_16x16x32_bf16(aq0, *(const s16x8*)kp, sacc[nf], 0, 0, 0);
      sacc[nf] = __builtin_amdgcn_mfma_f32_16x16x32_bf16(aq1, *(const s16x8*)(kp + 32), sacc[nf], 0, 0, 0);
    }

    float sv[4][4];
    const int rbase = qbase + w * 16 + 4 * kg;
#pragma unroll
    for (int nf = 0; nf < 4; ++nf) {
      const int cg = kvb + nf * 16 + lrow;
#pragma unroll
      for (int j = 0; j < 4; ++j) {
        float s = sacc[nf][j] * 0.125f;
        if (kt == qt && cg > rbase + j) s = -__builtin_inff();
        sv[nf][j] = s;
      }
    }

    float mj[4];
#pragma unroll
    for (int j = 0; j < 4; ++j)
      mj[j] = fmaxf(fmaxf(sv[0][j], sv[1][j]), fmaxf(sv[2][j], sv[3][j]));
#pragma unroll
    for (int off = 1; off < 16; off <<= 1)
#pragma unroll
      for (int j = 0; j < 4; ++j)
        mj[j] = fmaxf(mj[j], __shfl_xor(mj[j], off, 16));

    float rs[4];
#pragma unroll
    for (int j = 0; j < 4; ++j) {
      float newm = fmaxf(mrun[j], mj[j]);
      float sc = __expf(mrun[j] - newm);
      mrun[j] = newm;
      lrun[j] *= sc;
#pragma unroll
      for (int nf = 0; nf < 4; ++nf) oacc[nf][j] *= sc;
      rs[j] = 0.0f;
    }
#pragma unroll
    for (int nf = 0; nf < 4; ++nf)
#pragma unroll
      for (int j = 0; j < 4; ++j) {
        float p = __expf(sv[nf][j] - mrun[j]);
        rs[j] += p;
        plds[w][4 * kg + j][nf * 16 + lrow] = f2bf(p);
      }
#pragma unroll
    for (int off = 1; off < 16; off <<= 1)
#pragma unroll
      for (int j = 0; j < 4; ++j)
        rs[j] += __shfl_xor(rs[j], off, 16);
#pragma unroll
    for (int j = 0; j < 4; ++j) lrun[j] += rs[j];

    const s16x8 pa0 = *(const s16x8*)&plds[w][lrow][8 * kg];
    const s16x8 pa1 = *(const s16x8*)&plds[w][lrow][32 + 8 * kg];
#pragma unroll
    for (int nf = 0; nf < 4; ++nf) {
      const u16* vp = &vt[(size_t)(bh * 64 + nf * 16 + lrow) * T_ + kvb + 8 * kg];
      oacc[nf] = __builtin_amdgcn_mfma_f32_16x16x32_bf16(pa0, *(const s16x8*)vp, oacc[nf], 0, 0, 0);
      oacc[nf] = __builtin_amdgcn_mfma_f32_16x16x32_bf16(pa1, *(const s16x8*)(vp + 32), oacc[nf], 0, 0, 0);
    }
  }

#pragma unroll
  for (int nf = 0; nf < 4; ++nf)
#pragma unroll
    for (int j = 0; j < 4; ++j) {
      float v = oacc[nf][j] / lrun[j];
      const int t = qbase + w * 16 + 4 * kg + j;
      o[(size_t)(b * T_ + t) * DIM_ + h * 64 + nf * 16 + lrow] = f2bf(v);
    }
}

// ---------------- launch ----------------
extern "C" void kernel_launch(void* const* d_in, const int* in_sizes, int n_in,
                              void* d_out, int out_size, void* d_ws, size_t ws_size,
                              hipStream_t stream) {
  const float* x = (const float*)d_in[0];
  const float* w_qkv = (const float*)d_in[1];
  const float* w_out = (const float*)d_in[2];
  char* ws = (char*)d_ws;
  // workspace layout (bytes)
  u16* xb    = (u16*)(ws + 0);          // 4096*1024*2  = 8,388,608
  u16* wqkvb = (u16*)(ws + 8388608);    // 3072*1024*2  = 6,291,456
  u16* woutb = (u16*)(ws + 14680064);   // 1024*1024*2  = 2,097,152
  u16* qkvb  = (u16*)(ws + 16777216);   // 4096*3072*2  = 25,165,824
  u16* vtb   = (u16*)(ws + 41943040);   // 2*16*64*2048*2 = 8,388,608
  u16* attno = (u16*)(ws + 50331648);   // 4096*1024*2  = 8,388,608  (end ~56 MB)

  cvt_f32_bf16<<<4096, 256, 0, stream>>>(x, xb, 1048576);
  cvt_f32_bf16<<<3072, 256, 0, stream>>>(w_qkv, wqkvb, 786432);
  cvt_f32_bf16<<<1024, 256, 0, stream>>>(w_out, woutb, 262144);
  gemm_bt<0><<<dim3(24, 32), 256, 0, stream>>>(xb, wqkvb, qkvb, 4096, 3072, 1024);
  transpose_v<<<dim3(32, 32), 256, 0, stream>>>(qkvb, vtb);
  attn_fwd<<<dim3(32, 32), 256, 0, stream>>>(qkvb, vtb, attno);
  gemm_bt<1><<<dim3(8, 32), 256, 0, stream>>>(attno, woutb, (float*)d_out, 4096, 1024, 1024);
}

// Round 2
// 171.970 us; speedup vs baseline: 2.2339x; 2.2339x over previous
//
#include <hip/hip_runtime.h>

#define DIM_ 1024
#define HEADS_ 16
#define HD_ 64
#define T_ 2048
#define BATCH_ 2
#define QKVN_ 3072

typedef unsigned short u16;
typedef float f32x4 __attribute__((ext_vector_type(4)));
typedef short s16x8 __attribute__((ext_vector_type(8)));
typedef unsigned short u16x4 __attribute__((ext_vector_type(4)));

__device__ __forceinline__ u16 f2bf(float f) {
  unsigned u = __float_as_uint(f);
  u += 0x7fffu + ((u >> 16) & 1u);
  return (u16)(u >> 16);
}

// ---------------- fp32 -> bf16 conversion ----------------
__global__ __launch_bounds__(256) void cvt_f32_bf16(const float* __restrict__ in,
                                                    u16* __restrict__ out, int n4) {
  int i = blockIdx.x * 256 + threadIdx.x;
  if (i >= n4) return;
  float4 v = reinterpret_cast<const float4*>(in)[i];
  u16x4 o;
  o.x = f2bf(v.x); o.y = f2bf(v.y); o.z = f2bf(v.z); o.w = f2bf(v.w);
  reinterpret_cast<u16x4*>(out)[i] = o;
}

// ---------------- async global->LDS helper ----------------
__device__ __forceinline__ void gld_lds16(const void* g, void* l) {
  auto gp = (__attribute__((address_space(1))) char*)(unsigned long long)g;
  auto lp = (__attribute__((address_space(3))) char*)(unsigned int)(unsigned long long)l;
  __builtin_amdgcn_global_load_lds(gp, lp, 16, 0, 0);
}

// ---------------- GEMM: C[M][N] = A[M][K] * B[N][K]^T (bf16 in, fp32 acc) ----------------
template <int OUTF32>
__global__ __launch_bounds__(256) void gemm_bt(const u16* __restrict__ A,
                                               const u16* __restrict__ B,
                                               void* __restrict__ Cv,
                                               int M, int N, int K) {
  __shared__ __align__(16) u16 As[128 * 32];
  __shared__ __align__(16) u16 Bs[128 * 32];
  const int tid = threadIdx.x;
  const int lane = tid & 63;
  const int w = tid >> 6;
  const int wr = w >> 1, wc = w & 1;
  const int lrow = lane & 15, kg = lane >> 4;
  const int nt = blockIdx.x, mt = blockIdx.y;
  const u16* Ag = A + (size_t)(mt * 128) * K;
  const u16* Bg = B + (size_t)(nt * 128) * K;

  f32x4 acc[4][4];
#pragma unroll
  for (int i = 0; i < 4; ++i)
#pragma unroll
    for (int j = 0; j < 4; ++j) {
      f32x4 z = {0.f, 0.f, 0.f, 0.f};
      acc[i][j] = z;
    }

  const int e0 = tid * 8;
  const int row0 = e0 >> 5, kc0 = e0 & 31;
  const int row1 = row0 + 64, kc1 = kc0;
  const int ldsoff0 = (tid & ~63) * 16;
  const int ldsoff1 = (256 + (tid & ~63)) * 16;

  for (int k0 = 0; k0 < K; k0 += 32) {
    gld_lds16(Ag + (size_t)row0 * K + k0 + kc0, (char*)As + ldsoff0);
    gld_lds16(Ag + (size_t)row1 * K + k0 + kc1, (char*)As + ldsoff1);
    gld_lds16(Bg + (size_t)row0 * K + k0 + kc0, (char*)Bs + ldsoff0);
    gld_lds16(Bg + (size_t)row1 * K + k0 + kc1, (char*)Bs + ldsoff1);
    __syncthreads();
    s16x8 a[4], b[4];
#pragma unroll
    for (int mf = 0; mf < 4; ++mf)
      a[mf] = *(const s16x8*)&As[(wr * 64 + mf * 16 + lrow) * 32 + 8 * kg];
#pragma unroll
    for (int nf = 0; nf < 4; ++nf)
      b[nf] = *(const s16x8*)&Bs[(wc * 64 + nf * 16 + lrow) * 32 + 8 * kg];
#pragma unroll
    for (int mf = 0; mf < 4; ++mf)
#pragma unroll
      for (int nf = 0; nf < 4; ++nf)
        acc[mf][nf] = __builtin_amdgcn_mfma_f32_16x16x32_bf16(a[mf], b[nf], acc[mf][nf], 0, 0, 0);
    __syncthreads();
  }

#pragma unroll
  for (int mf = 0; mf < 4; ++mf)
#pragma unroll
    for (int nf = 0; nf < 4; ++nf)
#pragma unroll
      for (int j = 0; j < 4; ++j) {
        int r = mt * 128 + wr * 64 + mf * 16 + 4 * kg + j;
        int c = nt * 128 + wc * 64 + nf * 16 + lrow;
        float v = acc[mf][nf][j];
        if (OUTF32) ((float*)Cv)[(size_t)r * N + c] = v;
        else        ((u16*)Cv)[(size_t)r * N + c] = f2bf(v);
      }
}

// ---------------- V transpose: vt[b][h][d][t] = qkv[b*T+t][2048 + h*64 + d] ----------------
__global__ __launch_bounds__(256) void transpose_v(const u16* __restrict__ qkv,
                                                   u16* __restrict__ vt) {
  const int tt = blockIdx.x, bh = blockIdx.y;
  const int b = bh >> 4, h = bh & 15;
  const int d = threadIdx.x & 63;
  const int t16 = threadIdx.x >> 6;
  const int tbase = tt * 64 + t16 * 16;
  u16 tmp[16];
#pragma unroll
  for (int i = 0; i < 16; ++i)
    tmp[i] = qkv[(size_t)(b * T_ + tbase + i) * QKVN_ + 2048 + h * 64 + d];
  u16* dst = vt + (size_t)(bh * 64 + d) * T_ + tbase;
  *(s16x8*)dst = *(const s16x8*)tmp;
  *(s16x8*)(dst + 8) = *(const s16x8*)(tmp + 8);
}

// ---------------- causal flash attention ----------------
// Flattened grid 512 blocks, qt descending. Block = 4 waves x 32 q-rows = 128 rows.
// K/V tiles (64 kv x 64 d) double-buffered in padded LDS, shared by all waves.
__global__ __launch_bounds__(256) void attn_fwd(const u16* __restrict__ qkv,
                                                const u16* __restrict__ vt,
                                                u16* __restrict__ o) {
  const int gid = blockIdx.x;
  const int qt = 15 - (gid >> 5);      // long blocks first
  const int bh = gid & 31;
  const int b = bh >> 4, h = bh & 15;
  const int tid = threadIdx.x;
  const int w = tid >> 6, lane = tid & 63;
  const int lrow = lane & 15, kg = lane >> 4;
  const int qbase = qt * 128;
  const int wrow0 = qbase + w * 32;    // this wave's first q row
  const int wmax = wrow0 + 31;

  __shared__ __align__(16) u16 Ks[2][64][72];
  __shared__ __align__(16) u16 Vs[2][64][72];
  __shared__ __align__(16) u16 plds[4][32][72];

  // staging coords: 2 x 16B per thread per tile
  const int idx0 = tid, idx1 = 256 + tid;
  const int sr0 = idx0 >> 3, sc0 = (idx0 & 7) * 8;
  const int sr1 = idx1 >> 3, sc1 = (idx1 & 7) * 8;
  const u16* Kbase = qkv + (size_t)(b * T_) * QKVN_ + 1024 + h * 64;
  const u16* Vbase = vt + (size_t)(bh * 64) * T_;

  // Q fragments: rows wrow0 + rg*16 + lrow
  s16x8 aq[2][2];
#pragma unroll
  for (int rg = 0; rg < 2; ++rg) {
    const size_t qo = (size_t)(b * T_ + wrow0 + rg * 16 + lrow) * QKVN_ + h * 64 + 8 * kg;
    aq[rg][0] = *(const s16x8*)&qkv[qo];
    aq[rg][1] = *(const s16x8*)&qkv[qo + 32];
  }

  f32x4 oacc[2][4];
#pragma unroll
  for (int rg = 0; rg < 2; ++rg)
#pragma unroll
    for (int nf = 0; nf < 4; ++nf) {
      f32x4 z = {0.f, 0.f, 0.f, 0.f};
      oacc[rg][nf] = z;
    }
  float mrun[2][4], lrun[2][4];
#pragma unroll
  for (int rg = 0; rg < 2; ++rg)
#pragma unroll
    for (int j = 0; j < 4; ++j) { mrun[rg][j] = -__builtin_inff(); lrun[rg][j] = 0.0f; }

  const int nkt = 2 * qt + 2;   // kv tiles needed for this q block

  // prologue: stage tile 0
  s16x8 kr0, kr1, vr0, vr1;
  {
    kr0 = *(const s16x8*)(Kbase + (size_t)(sr0) * QKVN_ + sc0);
    kr1 = *(const s16x8*)(Kbase + (size_t)(sr1) * QKVN_ + sc1);
    vr0 = *(const s16x8*)(Vbase + (size_t)sr0 * T_ + sc0);
    vr1 = *(const s16x8*)(Vbase + (size_t)sr1 * T_ + sc1);
    *(s16x8*)&Ks[0][sr0][sc0] = kr0;
    *(s16x8*)&Ks[0][sr1][sc1] = kr1;
    *(s16x8*)&Vs[0][sr0][sc0] = vr0;
    *(s16x8*)&Vs[0][sr1][sc1] = vr1;
  }

  int cur = 0;
  for (int kt = 0; kt < nkt; ++kt) {
    const int kvb = kt * 64;
    const bool havenext = (kt + 1 < nkt);
    if (havenext) {
      const int nb = kvb + 64;
      kr0 = *(const s16x8*)(Kbase + (size_t)(nb + sr0) * QKVN_ + sc0);
      kr1 = *(const s16x8*)(Kbase + (size_t)(nb + sr1) * QKVN_ + sc1);
      vr0 = *(const s16x8*)(Vbase + (size_t)sr0 * T_ + nb + sc0);
      vr1 = *(const s16x8*)(Vbase + (size_t)sr1 * T_ + nb + sc1);
    }
    __syncthreads();   // buf[cur] visible to all waves

    if (kvb <= wmax) {
      // ---- QK^T ----
      f32x4 sacc[2][4];
#pragma unroll
      for (int rg = 0; rg < 2; ++rg)
#pragma unroll
        for (int nf = 0; nf < 4; ++nf) {
          f32x4 z = {0.f, 0.f, 0.f, 0.f};
          sacc[rg][nf] = z;
        }
#pragma unroll
      for (int nf = 0; nf < 4; ++nf)
#pragma unroll
        for (int ksl = 0; ksl < 2; ++ksl) {
          const s16x8 kf = *(const s16x8*)&Ks[cur][nf * 16 + lrow][ksl * 32 + 8 * kg];
          sacc[0][nf] = __builtin_amdgcn_mfma_f32_16x16x32_bf16(aq[0][ksl], kf, sacc[0][nf], 0, 0, 0);
          sacc[1][nf] = __builtin_amdgcn_mfma_f32_16x16x32_bf16(aq[1][ksl], kf, sacc[1][nf], 0, 0, 0);
        }

      // ---- softmax (online) ----
#pragma unroll
      for (int rg = 0; rg < 2; ++rg) {
        const int rbase = wrow0 + rg * 16 + 4 * kg;
        float sv[4][4];
#pragma unroll
        for (int nf = 0; nf < 4; ++nf) {
          const int cg = kvb + nf * 16 + lrow;
#pragma unroll
          for (int j = 0; j < 4; ++j) {
            float s = sacc[rg][nf][j] * 0.125f;
            if (cg > rbase + j) s = -__builtin_inff();
            sv[nf][j] = s;
          }
        }
        float mj[4];
#pragma unroll
        for (int j = 0; j < 4; ++j)
          mj[j] = fmaxf(fmaxf(sv[0][j], sv[1][j]), fmaxf(sv[2][j], sv[3][j]));
#pragma unroll
        for (int off = 1; off < 16; off <<= 1)
#pragma unroll
          for (int j = 0; j < 4; ++j)
            mj[j] = fmaxf(mj[j], __shfl_xor(mj[j], off, 16));
        float rs[4];
#pragma unroll
        for (int j = 0; j < 4; ++j) {
          float newm = fmaxf(mrun[rg][j], mj[j]);
          float sc = __expf(mrun[rg][j] - newm);
          mrun[rg][j] = newm;
          lrun[rg][j] *= sc;
#pragma unroll
          for (int nf = 0; nf < 4; ++nf) oacc[rg][nf][j] *= sc;
          rs[j] = 0.0f;
        }
#pragma unroll
        for (int nf = 0; nf < 4; ++nf)
#pragma unroll
          for (int j = 0; j < 4; ++j) {
            float p = __expf(sv[nf][j] - mrun[rg][j]);
            rs[j] += p;
            plds[w][rg * 16 + 4 * kg + j][nf * 16 + lrow] = f2bf(p);
          }
#pragma unroll
        for (int off = 1; off < 16; off <<= 1)
#pragma unroll
          for (int j = 0; j < 4; ++j)
            rs[j] += __shfl_xor(rs[j], off, 16);
#pragma unroll
        for (int j = 0; j < 4; ++j) lrun[rg][j] += rs[j];
      }

      // ---- P @ V ----
      s16x8 pa[2][2];
#pragma unroll
      for (int rg = 0; rg < 2; ++rg)
#pragma unroll
        for (int ksl = 0; ksl < 2; ++ksl)
          pa[rg][ksl] = *(const s16x8*)&plds[w][rg * 16 + lrow][ksl * 32 + 8 * kg];
#pragma unroll
      for (int nf = 0; nf < 4; ++nf)
#pragma unroll
        for (int ksl = 0; ksl < 2; ++ksl) {
          const s16x8 vf = *(const s16x8*)&Vs[cur][nf * 16 + lrow][ksl * 32 + 8 * kg];
          oacc[0][nf] = __builtin_amdgcn_mfma_f32_16x16x32_bf16(pa[0][ksl], vf, oacc[0][nf], 0, 0, 0);
          oacc[1][nf] = __builtin_amdgcn_mfma_f32_16x16x32_bf16(pa[1][ksl], vf, oacc[1][nf], 0, 0, 0);
        }
    }

    if (havenext) {
      const int nxt = cur ^ 1;
      *(s16x8*)&Ks[nxt][sr0][sc0] = kr0;
      *(s16x8*)&Ks[nxt][sr1][sc1] = kr1;
      *(s16x8*)&Vs[nxt][sr0][sc0] = vr0;
      *(s16x8*)&Vs[nxt][sr1][sc1] = vr1;
    }
    cur ^= 1;
  }

#pragma unroll
  for (int rg = 0; rg < 2; ++rg)
#pragma unroll
    for (int nf = 0; nf < 4; ++nf)
#pragma unroll
      for (int j = 0; j < 4; ++j) {
        float v = oacc[rg][nf][j] / lrun[rg][j];
        const int t = wrow0 + rg * 16 + 4 * kg + j;
        o[(size_t)(b * T_ + t) * DIM_ + h * 64 + nf * 16 + lrow] = f2bf(v);
      }
}

// ---------------- launch ----------------
extern "C" void kernel_launch(void* const* d_in, const int* in_sizes, int n_in,
                              void* d_out, int out_size, void* d_ws, size_t ws_size,
                              hipStream_t stream) {
  const float* x = (const float*)d_in[0];
  const float* w_qkv = (const float*)d_in[1];
  const float* w_out = (const float*)d_in[2];
  char* ws = (char*)d_ws;
  u16* xb    = (u16*)(ws + 0);          // 8,388,608
  u16* wqkvb = (u16*)(ws + 8388608);    // 6,291,456
  u16* woutb = (u16*)(ws + 14680064);   // 2,097,152
  u16* qkvb  = (u16*)(ws + 16777216);   // 25,165,824
  u16* vtb   = (u16*)(ws + 41943040);   // 8,388,608
  u16* attno = (u16*)(ws + 50331648);   // 8,388,608

  cvt_f32_bf16<<<4096, 256, 0, stream>>>(x, xb, 1048576);
  cvt_f32_bf16<<<3072, 256, 0, stream>>>(w_qkv, wqkvb, 786432);
  cvt_f32_bf16<<<1024, 256, 0, stream>>>(w_out, woutb, 262144);
  gemm_bt<0><<<dim3(24, 32), 256, 0, stream>>>(xb, wqkvb, qkvb, 4096, 3072, 1024);
  transpose_v<<<dim3(32, 32), 256, 0, stream>>>(qkvb, vtb);
  attn_fwd<<<512, 256, 0, stream>>>(qkvb, vtb, attno);
  gemm_bt<1><<<dim3(8, 32), 256, 0, stream>>>(attno, woutb, (float*)d_out, 4096, 1024, 1024);
}

// Round 3
// 159.235 us; speedup vs baseline: 2.4126x; 1.0800x over previous
//
#include <hip/hip_runtime.h>

#define DIM_ 1024
#define HEADS_ 16
#define HD_ 64
#define T_ 2048
#define BATCH_ 2
#define QKVN_ 3072

typedef unsigned short u16;
typedef float f32x4 __attribute__((ext_vector_type(4)));
typedef short s16x8 __attribute__((ext_vector_type(8)));
typedef unsigned short u16x4 __attribute__((ext_vector_type(4)));

__device__ __forceinline__ u16 f2bf(float f) {
  unsigned u = __float_as_uint(f);
  u += 0x7fffu + ((u >> 16) & 1u);
  return (u16)(u >> 16);
}

__device__ __forceinline__ float fexp2(float x) {
  float r;
  asm("v_exp_f32 %0, %1" : "=v"(r) : "v"(x));
  return r;
}

// ---------------- fp32 -> bf16 conversion ----------------
__global__ __launch_bounds__(256) void cvt_f32_bf16(const float* __restrict__ in,
                                                    u16* __restrict__ out, int n4) {
  int i = blockIdx.x * 256 + threadIdx.x;
  if (i >= n4) return;
  float4 v = reinterpret_cast<const float4*>(in)[i];
  u16x4 o;
  o.x = f2bf(v.x); o.y = f2bf(v.y); o.z = f2bf(v.z); o.w = f2bf(v.w);
  reinterpret_cast<u16x4*>(out)[i] = o;
}

// ---------------- async global->LDS helper ----------------
__device__ __forceinline__ void gld_lds16(const void* g, void* l) {
  auto gp = (__attribute__((address_space(1))) char*)(unsigned long long)g;
  auto lp = (__attribute__((address_space(3))) char*)(unsigned int)(unsigned long long)l;
  __builtin_amdgcn_global_load_lds(gp, lp, 16, 0, 0);
}

// ---------------- GEMM: C[M][N] = A[M][K] * B[N][K]^T (bf16 in, fp32 acc) ----------------
template <int OUTF32>
__global__ __launch_bounds__(256) void gemm_bt(const u16* __restrict__ A,
                                               const u16* __restrict__ B,
                                               void* __restrict__ Cv,
                                               int M, int N, int K) {
  __shared__ __align__(16) u16 As[128 * 32];
  __shared__ __align__(16) u16 Bs[128 * 32];
  const int tid = threadIdx.x;
  const int lane = tid & 63;
  const int w = tid >> 6;
  const int wr = w >> 1, wc = w & 1;
  const int lrow = lane & 15, kg = lane >> 4;
  const int nt = blockIdx.x, mt = blockIdx.y;
  const u16* Ag = A + (size_t)(mt * 128) * K;
  const u16* Bg = B + (size_t)(nt * 128) * K;

  f32x4 acc[4][4];
#pragma unroll
  for (int i = 0; i < 4; ++i)
#pragma unroll
    for (int j = 0; j < 4; ++j) {
      f32x4 z = {0.f, 0.f, 0.f, 0.f};
      acc[i][j] = z;
    }

  const int e0 = tid * 8;
  const int row0 = e0 >> 5, kc0 = e0 & 31;
  const int row1 = row0 + 64, kc1 = kc0;
  const int ldsoff0 = (tid & ~63) * 16;
  const int ldsoff1 = (256 + (tid & ~63)) * 16;

  for (int k0 = 0; k0 < K; k0 += 32) {
    gld_lds16(Ag + (size_t)row0 * K + k0 + kc0, (char*)As + ldsoff0);
    gld_lds16(Ag + (size_t)row1 * K + k0 + kc1, (char*)As + ldsoff1);
    gld_lds16(Bg + (size_t)row0 * K + k0 + kc0, (char*)Bs + ldsoff0);
    gld_lds16(Bg + (size_t)row1 * K + k0 + kc1, (char*)Bs + ldsoff1);
    __syncthreads();
    s16x8 a[4], b[4];
#pragma unroll
    for (int mf = 0; mf < 4; ++mf)
      a[mf] = *(const s16x8*)&As[(wr * 64 + mf * 16 + lrow) * 32 + 8 * kg];
#pragma unroll
    for (int nf = 0; nf < 4; ++nf)
      b[nf] = *(const s16x8*)&Bs[(wc * 64 + nf * 16 + lrow) * 32 + 8 * kg];
#pragma unroll
    for (int mf = 0; mf < 4; ++mf)
#pragma unroll
      for (int nf = 0; nf < 4; ++nf)
        acc[mf][nf] = __builtin_amdgcn_mfma_f32_16x16x32_bf16(a[mf], b[nf], acc[mf][nf], 0, 0, 0);
    __syncthreads();
  }

#pragma unroll
  for (int mf = 0; mf < 4; ++mf)
#pragma unroll
    for (int nf = 0; nf < 4; ++nf)
#pragma unroll
      for (int j = 0; j < 4; ++j) {
        int r = mt * 128 + wr * 64 + mf * 16 + 4 * kg + j;
        int c = nt * 128 + wc * 64 + nf * 16 + lrow;
        float v = acc[mf][nf][j];
        if (OUTF32) ((float*)Cv)[(size_t)r * N + c] = v;
        else        ((u16*)Cv)[(size_t)r * N + c] = f2bf(v);
      }
}

// ---------------- V transpose: vt[b][h][d][t] = qkv[b*T+t][2048 + h*64 + d] ----------------
__global__ __launch_bounds__(256) void transpose_v(const u16* __restrict__ qkv,
                                                   u16* __restrict__ vt) {
  const int tt = blockIdx.x, bh = blockIdx.y;
  const int b = bh >> 4, h = bh & 15;
  const int d = threadIdx.x & 63;
  const int t16 = threadIdx.x >> 6;
  const int tbase = tt * 64 + t16 * 16;
  u16 tmp[16];
#pragma unroll
  for (int i = 0; i < 16; ++i)
    tmp[i] = qkv[(size_t)(b * T_ + tbase + i) * QKVN_ + 2048 + h * 64 + d];
  u16* dst = vt + (size_t)(bh * 64 + d) * T_ + tbase;
  *(s16x8*)dst = *(const s16x8*)tmp;
  *(s16x8*)(dst + 8) = *(const s16x8*)(tmp + 8);
}

// ---------------- causal flash attention ----------------
// 512 blocks (qt descending x 32 bh), 512 threads = 8 waves x 16 q-rows = 128 rows.
// K/V tiles (64 kv x 64 d) double-buffered in padded LDS, shared by all 8 waves.
__global__ __launch_bounds__(512, 4) void attn_fwd(const u16* __restrict__ qkv,
                                                   const u16* __restrict__ vt,
                                                   u16* __restrict__ o) {
  const int gid = blockIdx.x;
  const int qt = 15 - (gid >> 5);      // long blocks first
  const int bh = gid & 31;
  const int b = bh >> 4, h = bh & 15;
  const int tid = threadIdx.x;
  const int w = tid >> 6, lane = tid & 63;
  const int lrow = lane & 15, kg = lane >> 4;
  const int qbase = qt * 128;
  const int wrow0 = qbase + w * 16;    // this wave's 16 q rows
  const int wmax = wrow0 + 15;
  const int diag = wmax & ~63;         // the single kv tile needing a causal mask

  __shared__ __align__(16) u16 Ks[2][64][72];
  __shared__ __align__(16) u16 Vs[2][64][72];
  __shared__ __align__(16) u16 plds[8][16][72];

  // staging: each of 512 threads moves one 16B chunk of K and one of V per tile
  const int sr = tid >> 3, scc = (tid & 7) * 8;
  const u16* Kbase = qkv + (size_t)(b * T_) * QKVN_ + 1024 + h * 64;
  const u16* Vbase = vt + (size_t)(bh * 64) * T_;

  // Q fragments (rows wrow0 + lrow)
  s16x8 aq0, aq1;
  {
    const size_t qo = (size_t)(b * T_ + wrow0 + lrow) * QKVN_ + h * 64 + 8 * kg;
    aq0 = *(const s16x8*)&qkv[qo];
    aq1 = *(const s16x8*)&qkv[qo + 32];
  }

  f32x4 oacc[4];
#pragma unroll
  for (int nf = 0; nf < 4; ++nf) {
    f32x4 z = {0.f, 0.f, 0.f, 0.f};
    oacc[nf] = z;
  }
  float mrun[4], lrun[4];
#pragma unroll
  for (int j = 0; j < 4; ++j) { mrun[j] = -__builtin_inff(); lrun[j] = 0.0f; }

  const float CEXP = 0.18033688011112042f;  // (1/8) * log2(e)
  const int nkt = 2 * qt + 2;

  // prologue: stage tile 0
  s16x8 kr, vr;
  kr = *(const s16x8*)(Kbase + (size_t)sr * QKVN_ + scc);
  vr = *(const s16x8*)(Vbase + (size_t)sr * T_ + scc);
  *(s16x8*)&Ks[0][sr][scc] = kr;
  *(s16x8*)&Vs[0][sr][scc] = vr;

  int cur = 0;
  for (int kt = 0; kt < nkt; ++kt) {
    const int kvb = kt * 64;
    const bool havenext = (kt + 1 < nkt);
    if (havenext) {                       // issue next-tile loads early
      const int nb = kvb + 64;
      kr = *(const s16x8*)(Kbase + (size_t)(nb + sr) * QKVN_ + scc);
      vr = *(const s16x8*)(Vbase + (size_t)sr * T_ + nb + scc);
    }
    __syncthreads();                      // buf[cur] visible to all waves

    if (kvb <= wmax) {
      // ---- QK^T ----
      f32x4 sacc[4];
#pragma unroll
      for (int nf = 0; nf < 4; ++nf) {
        f32x4 z = {0.f, 0.f, 0.f, 0.f};
        sacc[nf] = z;
      }
#pragma unroll
      for (int nf = 0; nf < 4; ++nf) {
        const s16x8 kf0 = *(const s16x8*)&Ks[cur][nf * 16 + lrow][8 * kg];
        const s16x8 kf1 = *(const s16x8*)&Ks[cur][nf * 16 + lrow][32 + 8 * kg];
        sacc[nf] = __builtin_amdgcn_mfma_f32_16x16x32_bf16(aq0, kf0, sacc[nf], 0, 0, 0);
        sacc[nf] = __builtin_amdgcn_mfma_f32_16x16x32_bf16(aq1, kf1, sacc[nf], 0, 0, 0);
      }

      // ---- causal mask (diagonal tile only; wave-uniform branch) ----
      if (kvb == diag) {
        const int r = wrow0 + 4 * kg;
#pragma unroll
        for (int nf = 0; nf < 4; ++nf) {
          const int cg = kvb + nf * 16 + lrow;
#pragma unroll
          for (int j = 0; j < 4; ++j)
            if (cg > r + j) sacc[nf][j] = -__builtin_inff();
        }
      }

      // ---- online softmax (exp2 domain, raw scores) ----
      float mj[4];
#pragma unroll
      for (int j = 0; j < 4; ++j)
        mj[j] = fmaxf(fmaxf(sacc[0][j], sacc[1][j]), fmaxf(sacc[2][j], sacc[3][j]));
#pragma unroll
      for (int off = 1; off < 16; off <<= 1)
#pragma unroll
        for (int j = 0; j < 4; ++j)
          mj[j] = fmaxf(mj[j], __shfl_xor(mj[j], off, 16));

      // defer-rescale (T13): skip rescale while growth <= 8 log2-units
      bool needfull = false;
#pragma unroll
      for (int j = 0; j < 4; ++j)
        needfull |= !((mj[j] - mrun[j]) * CEXP <= 8.0f);
      if (__any(needfull)) {
#pragma unroll
        for (int j = 0; j < 4; ++j) {
          float newm = fmaxf(mrun[j], mj[j]);
          float sc = fexp2((mrun[j] - newm) * CEXP);
          mrun[j] = newm;
          lrun[j] *= sc;
#pragma unroll
          for (int nf = 0; nf < 4; ++nf) oacc[nf][j] *= sc;
        }
      }
      float msc[4];
#pragma unroll
      for (int j = 0; j < 4; ++j) msc[j] = mrun[j] * CEXP;

      float rs[4] = {0.f, 0.f, 0.f, 0.f};
#pragma unroll
      for (int nf = 0; nf < 4; ++nf)
#pragma unroll
        for (int j = 0; j < 4; ++j) {
          float p = fexp2(__builtin_fmaf(sacc[nf][j], CEXP, -msc[j]));
          rs[j] += p;
          plds[w][4 * kg + j][nf * 16 + lrow] = f2bf(p);
        }
#pragma unroll
      for (int off = 1; off < 16; off <<= 1)
#pragma unroll
        for (int j = 0; j < 4; ++j)
          rs[j] += __shfl_xor(rs[j], off, 16);
#pragma unroll
      for (int j = 0; j < 4; ++j) lrun[j] += rs[j];

      // ---- P @ V ----
      const s16x8 pa0 = *(const s16x8*)&plds[w][lrow][8 * kg];
      const s16x8 pa1 = *(const s16x8*)&plds[w][lrow][32 + 8 * kg];
#pragma unroll
      for (int nf = 0; nf < 4; ++nf) {
        const s16x8 vf0 = *(const s16x8*)&Vs[cur][nf * 16 + lrow][8 * kg];
        const s16x8 vf1 = *(const s16x8*)&Vs[cur][nf * 16 + lrow][32 + 8 * kg];
        oacc[nf] = __builtin_amdgcn_mfma_f32_16x16x32_bf16(pa0, vf0, oacc[nf], 0, 0, 0);
        oacc[nf] = __builtin_amdgcn_mfma_f32_16x16x32_bf16(pa1, vf1, oacc[nf], 0, 0, 0);
      }
    }

    if (havenext) {                       // write-late into the other buffer
      *(s16x8*)&Ks[cur ^ 1][sr][scc] = kr;
      *(s16x8*)&Vs[cur ^ 1][sr][scc] = vr;
    }
    cur ^= 1;
  }

#pragma unroll
  for (int nf = 0; nf < 4; ++nf)
#pragma unroll
    for (int j = 0; j < 4; ++j) {
      float v = oacc[nf][j] / lrun[j];
      const int t = wrow0 + 4 * kg + j;
      o[(size_t)(b * T_ + t) * DIM_ + h * 64 + nf * 16 + lrow] = f2bf(v);
    }
}

// ---------------- launch ----------------
extern "C" void kernel_launch(void* const* d_in, const int* in_sizes, int n_in,
                              void* d_out, int out_size, void* d_ws, size_t ws_size,
                              hipStream_t stream) {
  const float* x = (const float*)d_in[0];
  const float* w_qkv = (const float*)d_in[1];
  const float* w_out = (const float*)d_in[2];
  char* ws = (char*)d_ws;
  u16* xb    = (u16*)(ws + 0);          // 8,388,608
  u16* wqkvb = (u16*)(ws + 8388608);    // 6,291,456
  u16* woutb = (u16*)(ws + 14680064);   // 2,097,152
  u16* qkvb  = (u16*)(ws + 16777216);   // 25,165,824
  u16* vtb   = (u16*)(ws + 41943040);   // 8,388,608
  u16* attno = (u16*)(ws + 50331648);   // 8,388,608

  cvt_f32_bf16<<<4096, 256, 0, stream>>>(x, xb, 1048576);
  cvt_f32_bf16<<<3072, 256, 0, stream>>>(w_qkv, wqkvb, 786432);
  cvt_f32_bf16<<<1024, 256, 0, stream>>>(w_out, woutb, 262144);
  gemm_bt<0><<<dim3(24, 32), 256, 0, stream>>>(xb, wqkvb, qkvb, 4096, 3072, 1024);
  transpose_v<<<dim3(32, 32), 256, 0, stream>>>(qkvb, vtb);
  attn_fwd<<<512, 512, 0, stream>>>(qkvb, vtb, attno);
  gemm_bt<1><<<dim3(8, 32), 256, 0, stream>>>(attno, woutb, (float*)d_out, 4096, 1024, 1024);
}